// Round 10
// baseline (462.151 us; speedup 1.0000x reference)
//
#include <hip/hip_runtime.h>
#include <math.h>

// Problem constants (fixed-shape problem)
#define B_  16
#define D_  37
#define F_  4096
#define I_  64
#define EPS 1e-5f
// softmax scale 1/sqrt(64) folded with log2(e) into q at projection time,
// so S_mfma = att*log2e and softmax is a raw exp2. |att|<=8 (LN rows have
// norm exactly 8) -> exp2(S) <= 2^11.6: no max pass, bf16-safe unnormalized P.
#define QSCALE 0.18033688011112042f
#define NQS 4           // stats q-split (partial-Z planes)
#define KSP 4           // out-kernel k-split (4 -> 4096 waves = 4/SIMD)

typedef unsigned short u16;
typedef __bf16 bf16x8 __attribute__((ext_vector_type(8)));
typedef __bf16 bf16x2v __attribute__((ext_vector_type(2)));
typedef float  f32x16 __attribute__((ext_vector_type(16)));
typedef float  f32x2v __attribute__((ext_vector_type(2)));
typedef unsigned int u32x4 __attribute__((ext_vector_type(4)));
typedef int i32x2 __attribute__((ext_vector_type(2)));

#define ZERO16 {0,0,0,0, 0,0,0,0, 0,0,0,0, 0,0,0,0}
#define MFMA32(a, b, c) __builtin_amdgcn_mfma_f32_32x32x16_bf16((a), (b), (c), 0, 0, 0)

#if __has_builtin(__builtin_amdgcn_exp2f)
#define EX2(x) __builtin_amdgcn_exp2f(x)
#else
#define EX2(x) exp2f(x)
#endif
#if __has_builtin(__builtin_amdgcn_rcpf)
#define RCP(x) __builtin_amdgcn_rcpf(x)
#else
#define RCP(x) (1.f / (x))
#endif

// fp32 -> bf16 RNE (scalar)
__device__ __forceinline__ u16 f2b(float f) {
  unsigned u = __builtin_bit_cast(unsigned, f);
  return (u16)((u + 0x7fffu + ((u >> 16) & 1u)) >> 16);
}
// bf16 bits -> fp32
__device__ __forceinline__ float b2f(u16 h) {
  return __builtin_bit_cast(float, (unsigned)h << 16);
}
// pack two fp32 -> bf16x2 (one v_cvt_pk_bf16_f32 where available)
__device__ __forceinline__ unsigned pk2(float lo, float hi) {
  f32x2v f = {lo, hi};
  bf16x2v h = __builtin_convertvector(f, bf16x2v);
  return __builtin_bit_cast(unsigned, h);
}

// half-wave register swap (v_permlane32_swap_b32 on gfx950)
__device__ __forceinline__ void plswap(unsigned& a, unsigned& b) {
#if __has_builtin(__builtin_amdgcn_permlane32_swap)
  i32x2 r = __builtin_amdgcn_permlane32_swap((int)a, (int)b, false, false);
  a = (unsigned)r[0];
  b = (unsigned)r[1];
#else
  const int lh = (int)((threadIdx.x & 63) >> 5);
  unsigned pa = (unsigned)__shfl_xor((int)a, 32, 64);
  unsigned pb = (unsigned)__shfl_xor((int)b, 32, 64);
  unsigned na = lh ? pb : a;
  unsigned nb = lh ? b : pa;
  a = na;
  b = nb;
#endif
}

// From one S^T 32x32 C-block (rows=k, cols=q), build two PV A-fragments
// (m=q, contraction k): f0 = k 0..15, f1 = k 16..31 of this block.
// C-reg r holds k=(r&3)+8*(r>>2)+4*lh; A-frag VGPR j needs k=lh*8+2j(+1).
__device__ __forceinline__ void build_af(const f32x16& s, bf16x8& f0, bf16x8& f1) {
  float e[16];
#pragma unroll
  for (int r = 0; r < 16; ++r) e[r] = EX2(s[r]);
  unsigned a = pk2(e[0], e[1]),   bq = pk2(e[2], e[3]);
  unsigned c = pk2(e[4], e[5]),   d  = pk2(e[6], e[7]);
  plswap(a, c);
  plswap(bq, d);
  u32x4 v0 = {a, bq, c, d};
  f0 = __builtin_bit_cast(bf16x8, v0);
  unsigned ee = pk2(e[8], e[9]),  ff = pk2(e[10], e[11]);
  unsigned g  = pk2(e[12], e[13]), h = pk2(e[14], e[15]);
  plswap(ee, g);
  plswap(ff, h);
  u32x4 v1 = {ee, ff, g, h};
  f1 = __builtin_bit_cast(bf16x8, v1);
}

// ---------------------------------------------------------------------------
// Swizzled LDS tiles (stats kernel only): logical [rows][64] bf16, elem (r,c)
// at r*64 + ((c>>3 ^ (r&7))<<3) + (c&7) -> b128-aligned, conflict-free.
// ---------------------------------------------------------------------------
__device__ __forceinline__ bf16x8 ldfrag(const u16* base, int row, int kb) {
  return *(const bf16x8*)(base + (row << 6) + ((kb ^ (row & 7)) << 3));
}
__device__ __forceinline__ void stage16(u16* dst, const u16* src, int c, int spitch) {
  const int r = c >> 3, cb = c & 7;
  const int4 v = *(const int4*)(src + (size_t)r * spitch + (cb << 3));
  *(int4*)(dst + (r << 6) + ((cb ^ (r & 7)) << 3)) = v;
}
__device__ __forceinline__ int soff_l(int c) {
  const int r = c >> 3, cb = c & 7;
  return (r << 6) + ((cb ^ (r & 7)) << 3);
}
__device__ __forceinline__ int soff_g(int c, int spitch) {
  return (c >> 3) * spitch + ((c & 7) << 3);
}

// ---------------------------------------------------------------------------
// Kernel 1: qkv projection + LayerNorm -> bf16. q pre-scaled by QSCALE.
// d-outer loop (W read once per d); x/W straight from global (L1-resident).
// v written transposed vt[b][i][f] (LDS tile) for the out kernel.
// ---------------------------------------------------------------------------
__global__ __launch_bounds__(256) void qkv_ln_k(
    const float* __restrict__ x,
    const float* __restrict__ Wq, const float* __restrict__ Wk,
    const float* __restrict__ Wv,
    u16* __restrict__ qn, u16* __restrict__ kn, u16* __restrict__ vt) {
  __shared__ __align__(16) u16 vtile[64 * 72];

  const int t = threadIdx.x, lane = t & 63, w = t >> 6;
  const int b = blockIdx.y, f0 = blockIdx.x * 64;
  const int fl0 = w * 16;

  float hq[16], hk[16], hv[16];
#pragma unroll
  for (int i = 0; i < 16; ++i) { hq[i] = 0.f; hk[i] = 0.f; hv[i] = 0.f; }

  const float* xb = x + (size_t)b * D_ * F_ + f0 + fl0;
#pragma unroll 1
  for (int d = 0; d < D_; ++d) {
    const float wqv = Wq[d * I_ + lane];
    const float wkv = Wk[d * I_ + lane];
    const float wvv = Wv[d * I_ + lane];
    float xv[16];
#pragma unroll
    for (int g = 0; g < 4; ++g)
      *(float4*)&xv[g * 4] = *(const float4*)(xb + (size_t)d * F_ + g * 4);
#pragma unroll
    for (int i = 0; i < 16; ++i) {
      hq[i] = fmaf(xv[i], wqv, hq[i]);
      hk[i] = fmaf(xv[i], wkv, hk[i]);
      hv[i] = fmaf(xv[i], wvv, hv[i]);
    }
  }

  auto lnorm = [&](float a) -> float {
    float s = a;
#pragma unroll
    for (int o = 32; o > 0; o >>= 1) s += __shfl_xor(s, o, 64);
    const float mu = s * (1.f / 64.f);
    const float d0 = a - mu;
    float v = d0 * d0;
#pragma unroll
    for (int o = 32; o > 0; o >>= 1) v += __shfl_xor(v, o, 64);
    return d0 * rsqrtf(v * (1.f / 64.f) + EPS);
  };

#pragma unroll
  for (int i = 0; i < 16; ++i) {
    const size_t fo = ((size_t)b * F_ + f0 + fl0 + i) * I_ + lane;
    qn[fo] = f2b(lnorm(hq[i]) * QSCALE);
    kn[fo] = f2b(lnorm(hk[i]));
    vtile[lane * 72 + fl0 + i] = f2b(lnorm(hv[i]));
  }
  __syncthreads();
  for (int p = 0; p < 2; ++p) {
    const int c = p * 256 + t;
    const int r = c >> 3, off = (c & 7) * 8;
    const int4 v = *(const int4*)&vtile[r * 72 + off];
    *(int4*)(vt + ((size_t)b * I_ + r) * F_ + f0 + off) = v;
  }
}

// ---------------------------------------------------------------------------
// Kernel 2: partial column-softmax sums zp[qh][b][k] = sum_{q in quarter}
// exp2(S). 256 thr / 4 waves, (256-k tile, b, q-quarter). K tile (32 KB)
// staged once -> 64-k B-fragments hoisted -> LDS reused as double-buffered
// Q stream. NQS=4 -> 1024 blocks = 4 blocks/CU, 16 waves/CU.
// ---------------------------------------------------------------------------
__global__ __launch_bounds__(256, 4) void attn_stats_k(
    const u16* __restrict__ qn, const u16* __restrict__ kn,
    float* __restrict__ zp) {
  __shared__ __align__(16) u16 sm[16384];   // 32 KB

  const int t = threadIdx.x, lane = t & 63, w = t >> 6;
  const int l31 = lane & 31, lh = lane >> 5;
  const int b = blockIdx.y, k0 = blockIdx.x * 256, qh = blockIdx.z;

  const u16* kb = kn + ((size_t)b * F_ + k0) * I_;
#pragma unroll
  for (int p = 0; p < 8; ++p) stage16(sm, kb, p * 256 + t, 64);
  __syncthreads();
  bf16x8 kf[2][4];
#pragma unroll
  for (int kb2 = 0; kb2 < 2; ++kb2)
#pragma unroll
    for (int ic = 0; ic < 4; ++ic)
      kf[kb2][ic] = ldfrag(sm + (w * 64 + kb2 * 32) * 64, l31, ic * 2 + lh);
  __syncthreads();                          // frag reads done before reuse

  int qoff_l[2], qoff_g[2];
#pragma unroll
  for (int p = 0; p < 2; ++p) {
    const int c = p * 256 + t;
    qoff_l[p] = soff_l(c);
    qoff_g[p] = soff_g(c, 64);
  }

  const u16* qsrc = qn + ((size_t)b * F_ + qh * (F_ / NQS)) * I_;
#pragma unroll
  for (int p = 0; p < 2; ++p)               // chunk 0 into buffer 0
    *(int4*)(sm + qoff_l[p]) = *(const int4*)(qsrc + qoff_g[p]);
  qsrc += 64 * I_;

  float Zc[2][2] = {{0.f, 0.f}, {0.f, 0.f}};  // [qb][kb]
  const int NC = F_ / NQS / 64;             // 16 chunks

  for (int c = 0; c < NC; ++c) {
    const int cur = (c & 1) * 4096;
    __syncthreads();                        // cur staged; nxt's old readers done
    if (c + 1 < NC) {
      const int nxt = cur ^ 4096;
#pragma unroll
      for (int p = 0; p < 2; ++p)
        *(int4*)(sm + nxt + qoff_l[p]) = *(const int4*)(qsrc + qoff_g[p]);
      qsrc += 64 * I_;
    }

    f32x16 a00 = ZERO16, a01 = ZERO16, a10 = ZERO16, a11 = ZERO16;
#pragma unroll
    for (int ic = 0; ic < 4; ++ic) {
      const bf16x8 q0f = ldfrag(sm + cur, l31, ic * 2 + lh);
      const bf16x8 q1f = ldfrag(sm + cur + 32 * 64, l31, ic * 2 + lh);
      a00 = MFMA32(q0f, kf[0][ic], a00);
      a01 = MFMA32(q0f, kf[1][ic], a01);
      a10 = MFMA32(q1f, kf[0][ic], a10);
      a11 = MFMA32(q1f, kf[1][ic], a11);
    }
#pragma unroll
    for (int r = 0; r < 16; ++r) {
      Zc[0][0] += EX2(a00[r]);
      Zc[0][1] += EX2(a01[r]);
      Zc[1][0] += EX2(a10[r]);
      Zc[1][1] += EX2(a11[r]);
    }
  }

#pragma unroll
  for (int kb2 = 0; kb2 < 2; ++kb2) {
    float Zt = Zc[0][kb2] + Zc[1][kb2];
    Zt += __shfl_xor(Zt, 32, 64);
    if (lane < 32)
      zp[((size_t)qh * B_ + b) * F_ + k0 + w * 64 + kb2 * 32 + lane] = Zt;
  }
}

// ---------------------------------------------------------------------------
// Kernel 3: fold 1/Z_k into V rows, in place: vt[b][i][k] *= 1/sum(zp planes).
// ---------------------------------------------------------------------------
__global__ __launch_bounds__(256) void vscale_k(u16* __restrict__ vt,
                                                const float* __restrict__ zp) {
  const int b = blockIdx.y;
  const int off = (blockIdx.x * 256 + (int)threadIdx.x) * 8;  // within I_*F_
  const int k = off & (F_ - 1);
  u16* p = vt + (size_t)b * I_ * F_ + off;
  const float* z0 = zp + (size_t)b * F_ + k;
  int4 raw = *(const int4*)p;
  u16 es[8], os[8];
  *(int4*)es = raw;
#pragma unroll
  for (int j = 0; j < 8; ++j) {
    float z = z0[j];
#pragma unroll
    for (int pl = 1; pl < NQS; ++pl) z += z0[(size_t)pl * B_ * F_ + j];
    os[j] = f2b(b2f(es[j]) * RCP(z));
  }
  *(int4*)p = *(int4*)os;
}

// ---------------------------------------------------------------------------
// Kernel 4: partial out over a k-quarter, NO LDS / NO BARRIERS. One wave
// (64 thr) per block, owning 64 q. All MFMA operands direct from global
// (16B/lane): Q B-frags (hoisted), V B-frags (loaded at chunk TOP: covered
// by S-MFMA + build_af ~400 cyc), K A-frags (pipelined 1 chunk ahead).
// KSP=4 -> 4096 waves = 16/CU = 4 waves/SIMD (latency hiding; VGPR<=128).
// 1-D grid, XCD swizzle: bid%8 == g%8 where g=(b,ks) -> each K/V stream
// pinned to one XCD; 8 streams x 256 KB = 2 MB < 4 MB L2 (R8 lesson).
// ks=0 -> fp32 out; ks>0 -> bf16 partial plane (reduce_k folds 3).
// ---------------------------------------------------------------------------
__global__ __launch_bounds__(64, 4) void attn_out_k(
    const u16* __restrict__ qn, const u16* __restrict__ kn,
    const u16* __restrict__ vt, float* __restrict__ out,
    u16* __restrict__ pout) {
  const int lane = threadIdx.x & 63;
  const int l31 = lane & 31, lh = lane >> 5;

  const int bid = blockIdx.x;
  const int g = bid & (B_ * KSP - 1);       // group: same g -> same XCD (mod 8)
  const int qt = bid >> 6;                  // 64 q-tiles
  const int b = g >> 2, ks = g & 3;
  const int q0 = qt * 64;

  // hoist Q B-fragments (8 x 16B direct global loads)
  const u16* qbase = qn + ((size_t)b * F_ + q0) * I_;
  bf16x8 qf[2][4];
#pragma unroll
  for (int qb2 = 0; qb2 < 2; ++qb2)
#pragma unroll
    for (int ic = 0; ic < 4; ++ic)
      qf[qb2][ic] = *(const bf16x8*)(qbase + (qb2 * 32 + l31) * I_ + ic * 16 + lh * 8);

  const int kofs = ks * (F_ / KSP);
  const u16* kp = kn + ((size_t)b * F_ + kofs) * I_ + l31 * I_ + lh * 8;
  const u16* vp = vt + (size_t)b * I_ * F_ + kofs + (size_t)l31 * F_ + lh * 8;

  // preload K A-frags for chunk 0
  bf16x8 ak[2][4];
#pragma unroll
  for (int kh = 0; kh < 2; ++kh)
#pragma unroll
    for (int ic = 0; ic < 4; ++ic)
      ak[kh][ic] = *(const bf16x8*)(kp + kh * 32 * I_ + ic * 16);

  f32x16 o00 = ZERO16, o01 = ZERO16, o10 = ZERO16, o11 = ZERO16; // [qb][ih]
  const int NC = F_ / KSP / 64;             // 16 chunks of 64 k

  for (int c = 0; c < NC; ++c) {
    // V B-frags for THIS chunk, issued first: S-MFMA + build_af cover them
    bf16x8 bv[2][4];                        // [ih][kq]
#pragma unroll
    for (int ih = 0; ih < 2; ++ih)
#pragma unroll
      for (int kq = 0; kq < 4; ++kq)
        bv[ih][kq] = *(const bf16x8*)(vp + (size_t)ih * 32 * F_ + c * 64 + kq * 16);

    // S^T = K x Q(own 64q): rows=k (2 halves), cols=q (2 blocks)
    f32x16 s00 = ZERO16, s01 = ZERO16, s10 = ZERO16, s11 = ZERO16; // [kh][qb]
#pragma unroll
    for (int ic = 0; ic < 4; ++ic) {
      s00 = MFMA32(ak[0][ic], qf[0][ic], s00);
      s01 = MFMA32(ak[0][ic], qf[1][ic], s01);
      s10 = MFMA32(ak[1][ic], qf[0][ic], s10);
      s11 = MFMA32(ak[1][ic], qf[1][ic], s11);
    }

    // K A-frags for next chunk (cover: build_af + PV)
    if (c + 1 < NC) {
      const u16* kpn = kp + (size_t)(c + 1) * 64 * I_;
#pragma unroll
      for (int kh = 0; kh < 2; ++kh)
#pragma unroll
        for (int ic = 0; ic < 4; ++ic)
          ak[kh][ic] = *(const bf16x8*)(kpn + kh * 32 * I_ + ic * 16);
    }

    // exp2 + in-register transpose into PV A-fragments per q-block
    bf16x8 af0[4], af1[4];
    build_af(s00, af0[0], af0[1]);
    build_af(s10, af0[2], af0[3]);
    build_af(s01, af1[0], af1[1]);
    build_af(s11, af1[2], af1[3]);

    // O += P(64q x 64k) * V'(64k x 64i), two i-halves
#pragma unroll
    for (int kq = 0; kq < 4; ++kq) {
      o00 = MFMA32(af0[kq], bv[0][kq], o00);
      o01 = MFMA32(af0[kq], bv[1][kq], o01);
      o10 = MFMA32(af1[kq], bv[0][kq], o10);
      o11 = MFMA32(af1[kq], bv[1][kq], o11);
    }
  }

  if (ks == 0) {
    float* ob = out + ((size_t)b * F_ + q0) * I_;
#pragma unroll
    for (int r = 0; r < 16; ++r) {
      const int qr = (r & 3) + 8 * (r >> 2) + 4 * lh;   // C/D row mapping
      ob[(size_t)qr * I_ + l31]              = o00[r];
      ob[(size_t)qr * I_ + 32 + l31]         = o01[r];
      ob[(size_t)(32 + qr) * I_ + l31]       = o10[r];
      ob[(size_t)(32 + qr) * I_ + 32 + l31]  = o11[r];
    }
  } else {
    u16* pb = pout + (size_t)(ks - 1) * B_ * F_ * I_ + ((size_t)b * F_ + q0) * I_;
#pragma unroll
    for (int r = 0; r < 16; ++r) {
      const int qr = (r & 3) + 8 * (r >> 2) + 4 * lh;
      pb[(size_t)qr * I_ + l31]              = f2b(o00[r]);
      pb[(size_t)qr * I_ + 32 + l31]         = f2b(o01[r]);
      pb[(size_t)(32 + qr) * I_ + l31]       = f2b(o10[r]);
      pb[(size_t)(32 + qr) * I_ + 32 + l31]  = f2b(o11[r]);
    }
  }
}

// ---------------------------------------------------------------------------
// Kernel 5: out += sum of 3 bf16 partial planes. 8 elems/thread.
// ---------------------------------------------------------------------------
__global__ __launch_bounds__(256) void reduce_k(float* __restrict__ out,
                                                const u16* __restrict__ pout) {
  const size_t NBF = (size_t)B_ * F_ * I_;
  const size_t i = ((size_t)blockIdx.x * 256 + threadIdx.x) * 8;
  float a[8];
  *(float4*)&a[0] = *(const float4*)(out + i);
  *(float4*)&a[4] = *(const float4*)(out + i + 4);
#pragma unroll
  for (int pl = 0; pl < KSP - 1; ++pl) {
    int4 praw = *(const int4*)(pout + pl * NBF + i);
    u16 es[8];
    *(int4*)es = praw;
#pragma unroll
    for (int j = 0; j < 8; ++j) a[j] += b2f(es[j]);
  }
  *(float4*)(out + i)     = *(float4*)&a[0];
  *(float4*)(out + i + 4) = *(float4*)&a[4];
}

// ---------------------------------------------------------------------------
extern "C" void kernel_launch(void* const* d_in, const int* in_sizes, int n_in,
                              void* d_out, int out_size, void* d_ws,
                              size_t ws_size, hipStream_t stream) {
  const float* x  = (const float*)d_in[0];
  const float* Wq = (const float*)d_in[1];
  const float* Wk = (const float*)d_in[2];
  const float* Wv = (const float*)d_in[3];
  float* out = (float*)d_out;

  // workspace: qn, kn, vt (bf16, B*F*I each); zp (f32 [NQS][B][F]);
  //            pout (bf16 [KSP-1][B][F][I] k-split partials)
  const size_t NBF = (size_t)B_ * F_ * I_;
  u16* qn   = (u16*)d_ws;
  u16* kn   = qn + NBF;
  u16* vt   = kn + NBF;
  float* zp = (float*)(vt + NBF);
  u16* pout = (u16*)(zp + (size_t)NQS * B_ * F_);

  qkv_ln_k<<<dim3(F_ / 64, B_), 256, 0, stream>>>(x, Wq, Wk, Wv, qn, kn, vt);
  attn_stats_k<<<dim3(F_ / 256, B_, NQS), 256, 0, stream>>>(qn, kn, zp);
  vscale_k<<<dim3(I_ * F_ / 2048, B_), 256, 0, stream>>>(vt, zp);
  attn_out_k<<<dim3((F_ / 64) * B_ * KSP), 64, 0, stream>>>(qn, kn, vt, out, pout);
  reduce_k<<<dim3((int)(NBF / 2048)), 256, 0, stream>>>(out, pout);
}

// Round 11
// 258.523 us; speedup vs baseline: 1.7877x; 1.7877x over previous
//
#include <hip/hip_runtime.h>
#include <math.h>

// Problem constants (fixed-shape problem)
#define B_  16
#define D_  37
#define F_  4096
#define I_  64
#define EPS 1e-5f
// softmax scale 1/sqrt(64) folded with log2(e) into q at projection time,
// so S_mfma = att*log2e and softmax is a raw exp2. |att|<=8 (LN rows have
// norm exactly 8) -> exp2(S) <= 2^11.6: no max pass needed.
#define QSCALE 0.18033688011112042f
#define NQS 4           // stats q-split (partial-Z planes)
#define KSP 2           // out-kernel k-split

typedef unsigned short u16;
typedef __bf16 bf16x8 __attribute__((ext_vector_type(8)));
typedef __bf16 bf16x2v __attribute__((ext_vector_type(2)));
typedef float  f32x16 __attribute__((ext_vector_type(16)));
typedef float  f32x2v __attribute__((ext_vector_type(2)));
typedef unsigned int u32x4 __attribute__((ext_vector_type(4)));
typedef int i32x2 __attribute__((ext_vector_type(2)));

#define ZERO16 {0,0,0,0, 0,0,0,0, 0,0,0,0, 0,0,0,0}
#define MFMA32(a, b, c) __builtin_amdgcn_mfma_f32_32x32x16_bf16((a), (b), (c), 0, 0, 0)

#if __has_builtin(__builtin_amdgcn_exp2f)
#define EX2(x) __builtin_amdgcn_exp2f(x)
#else
#define EX2(x) exp2f(x)
#endif
#if __has_builtin(__builtin_amdgcn_logf)
#define LG2(x) __builtin_amdgcn_logf(x)
#else
#define LG2(x) log2f(x)
#endif

// fp32 -> bf16 RNE (scalar)
__device__ __forceinline__ u16 f2b(float f) {
  unsigned u = __builtin_bit_cast(unsigned, f);
  return (u16)((u + 0x7fffu + ((u >> 16) & 1u)) >> 16);
}
// bf16 bits -> fp32
__device__ __forceinline__ float b2f(u16 h) {
  return __builtin_bit_cast(float, (unsigned)h << 16);
}
// pack two fp32 -> bf16x2 (one v_cvt_pk_bf16_f32 where available)
__device__ __forceinline__ unsigned pk2(float lo, float hi) {
  f32x2v f = {lo, hi};
  bf16x2v h = __builtin_convertvector(f, bf16x2v);
  return __builtin_bit_cast(unsigned, h);
}

// half-wave register swap (v_permlane32_swap_b32 on gfx950)
__device__ __forceinline__ void plswap(unsigned& a, unsigned& b) {
#if __has_builtin(__builtin_amdgcn_permlane32_swap)
  i32x2 r = __builtin_amdgcn_permlane32_swap((int)a, (int)b, false, false);
  a = (unsigned)r[0];
  b = (unsigned)r[1];
#else
  const int lh = (int)((threadIdx.x & 63) >> 5);
  unsigned pa = (unsigned)__shfl_xor((int)a, 32, 64);
  unsigned pb = (unsigned)__shfl_xor((int)b, 32, 64);
  unsigned na = lh ? pb : a;
  unsigned nb = lh ? b : pa;
  a = na;
  b = nb;
#endif
}

// From one S^T 32x32 C-block (rows=k, cols=q), build two PV A-fragments
// (m=q, contraction k): f0 = k 0..15, f1 = k 16..31 of this block.
// C-reg r holds k=(r&3)+8*(r>>2)+4*lh; A-frag VGPR j needs k=lh*8+2j(+1).
__device__ __forceinline__ void build_af(const f32x16& s, bf16x8& f0, bf16x8& f1) {
  float e[16];
#pragma unroll
  for (int r = 0; r < 16; ++r) e[r] = EX2(s[r]);
  unsigned a = pk2(e[0], e[1]),   bq = pk2(e[2], e[3]);
  unsigned c = pk2(e[4], e[5]),   d  = pk2(e[6], e[7]);
  plswap(a, c);
  plswap(bq, d);
  u32x4 v0 = {a, bq, c, d};
  f0 = __builtin_bit_cast(bf16x8, v0);
  unsigned ee = pk2(e[8], e[9]),  ff = pk2(e[10], e[11]);
  unsigned g  = pk2(e[12], e[13]), h = pk2(e[14], e[15]);
  plswap(ee, g);
  plswap(ff, h);
  u32x4 v1 = {ee, ff, g, h};
  f1 = __builtin_bit_cast(bf16x8, v1);
}

// ---------------------------------------------------------------------------
// Swizzled LDS tiles: logical [rows][64] bf16, elem (r,c) at
//   r*64 + ((c>>3 ^ (r&7))<<3) + (c&7) -> b128-aligned, conflict-free.
// ---------------------------------------------------------------------------
__device__ __forceinline__ bf16x8 ldfrag(const u16* base, int row, int kb) {
  return *(const bf16x8*)(base + (row << 6) + ((kb ^ (row & 7)) << 3));
}
__device__ __forceinline__ void stage16(u16* dst, const u16* src, int c, int spitch) {
  const int r = c >> 3, cb = c & 7;
  const int4 v = *(const int4*)(src + (size_t)r * spitch + (cb << 3));
  *(int4*)(dst + (r << 6) + ((cb ^ (r & 7)) << 3)) = v;
}
__device__ __forceinline__ int soff_l(int c) {
  const int r = c >> 3, cb = c & 7;
  return (r << 6) + ((cb ^ (r & 7)) << 3);
}
__device__ __forceinline__ int soff_g(int c, int spitch) {
  return (c >> 3) * spitch + ((c & 7) << 3);
}

// ---------------------------------------------------------------------------
// Kernel 1: qkv projection + LayerNorm -> bf16. q pre-scaled by QSCALE.
// d-outer loop (W read once per d); x/W straight from global (L1-resident).
// v written transposed vt[b][i][f] (LDS tile) for the out kernel.
// ---------------------------------------------------------------------------
__global__ __launch_bounds__(256) void qkv_ln_k(
    const float* __restrict__ x,
    const float* __restrict__ Wq, const float* __restrict__ Wk,
    const float* __restrict__ Wv,
    u16* __restrict__ qn, u16* __restrict__ kn, u16* __restrict__ vt) {
  __shared__ __align__(16) u16 vtile[64 * 72];

  const int t = threadIdx.x, lane = t & 63, w = t >> 6;
  const int b = blockIdx.y, f0 = blockIdx.x * 64;
  const int fl0 = w * 16;

  float hq[16], hk[16], hv[16];
#pragma unroll
  for (int i = 0; i < 16; ++i) { hq[i] = 0.f; hk[i] = 0.f; hv[i] = 0.f; }

  const float* xb = x + (size_t)b * D_ * F_ + f0 + fl0;
#pragma unroll 1
  for (int d = 0; d < D_; ++d) {
    const float wqv = Wq[d * I_ + lane];
    const float wkv = Wk[d * I_ + lane];
    const float wvv = Wv[d * I_ + lane];
    float xv[16];
#pragma unroll
    for (int g = 0; g < 4; ++g)
      *(float4*)&xv[g * 4] = *(const float4*)(xb + (size_t)d * F_ + g * 4);
#pragma unroll
    for (int i = 0; i < 16; ++i) {
      hq[i] = fmaf(xv[i], wqv, hq[i]);
      hk[i] = fmaf(xv[i], wkv, hk[i]);
      hv[i] = fmaf(xv[i], wvv, hv[i]);
    }
  }

  auto lnorm = [&](float a) -> float {
    float s = a;
#pragma unroll
    for (int o = 32; o > 0; o >>= 1) s += __shfl_xor(s, o, 64);
    const float mu = s * (1.f / 64.f);
    const float d0 = a - mu;
    float v = d0 * d0;
#pragma unroll
    for (int o = 32; o > 0; o >>= 1) v += __shfl_xor(v, o, 64);
    return d0 * rsqrtf(v * (1.f / 64.f) + EPS);
  };

#pragma unroll
  for (int i = 0; i < 16; ++i) {
    const size_t fo = ((size_t)b * F_ + f0 + fl0 + i) * I_ + lane;
    qn[fo] = f2b(lnorm(hq[i]) * QSCALE);
    kn[fo] = f2b(lnorm(hk[i]));
    vtile[lane * 72 + fl0 + i] = f2b(lnorm(hv[i]));
  }
  __syncthreads();
  for (int p = 0; p < 2; ++p) {
    const int c = p * 256 + t;
    const int r = c >> 3, off = (c & 7) * 8;
    const int4 v = *(const int4*)&vtile[r * 72 + off];
    *(int4*)(vt + ((size_t)b * I_ + r) * F_ + f0 + off) = v;
  }
}

// ---------------------------------------------------------------------------
// Kernel 2: partial column-softmax sums zp[qh][b][k] = sum_{q in quarter}
// exp2(S). 256 thr / 4 waves, (256-k tile, b, q-quarter). K tile (32 KB)
// staged once -> 64-k B-fragments hoisted -> LDS reused as double-buffered
// Q stream. NQS=4 -> 1024 blocks = 4 blocks/CU, 16 waves/CU.
// ---------------------------------------------------------------------------
__global__ __launch_bounds__(256, 4) void attn_stats_k(
    const u16* __restrict__ qn, const u16* __restrict__ kn,
    float* __restrict__ zp) {
  __shared__ __align__(16) u16 sm[16384];   // 32 KB

  const int t = threadIdx.x, lane = t & 63, w = t >> 6;
  const int l31 = lane & 31, lh = lane >> 5;
  const int b = blockIdx.y, k0 = blockIdx.x * 256, qh = blockIdx.z;

  const u16* kb = kn + ((size_t)b * F_ + k0) * I_;
#pragma unroll
  for (int p = 0; p < 8; ++p) stage16(sm, kb, p * 256 + t, 64);
  __syncthreads();
  bf16x8 kf[2][4];
#pragma unroll
  for (int kb2 = 0; kb2 < 2; ++kb2)
#pragma unroll
    for (int ic = 0; ic < 4; ++ic)
      kf[kb2][ic] = ldfrag(sm + (w * 64 + kb2 * 32) * 64, l31, ic * 2 + lh);
  __syncthreads();                          // frag reads done before reuse

  int qoff_l[2], qoff_g[2];
#pragma unroll
  for (int p = 0; p < 2; ++p) {
    const int c = p * 256 + t;
    qoff_l[p] = soff_l(c);
    qoff_g[p] = soff_g(c, 64);
  }

  const u16* qsrc = qn + ((size_t)b * F_ + qh * (F_ / NQS)) * I_;
#pragma unroll
  for (int p = 0; p < 2; ++p)               // chunk 0 into buffer 0
    *(int4*)(sm + qoff_l[p]) = *(const int4*)(qsrc + qoff_g[p]);
  qsrc += 64 * I_;

  float Zc[2][2] = {{0.f, 0.f}, {0.f, 0.f}};  // [qb][kb]
  const int NC = F_ / NQS / 64;             // 16 chunks

  for (int c = 0; c < NC; ++c) {
    const int cur = (c & 1) * 4096;
    __syncthreads();                        // cur staged; nxt's old readers done
    if (c + 1 < NC) {
      const int nxt = cur ^ 4096;
#pragma unroll
      for (int p = 0; p < 2; ++p)
        *(int4*)(sm + nxt + qoff_l[p]) = *(const int4*)(qsrc + qoff_g[p]);
      qsrc += 64 * I_;
    }

    f32x16 a00 = ZERO16, a01 = ZERO16, a10 = ZERO16, a11 = ZERO16;
#pragma unroll
    for (int ic = 0; ic < 4; ++ic) {
      const bf16x8 q0f = ldfrag(sm + cur, l31, ic * 2 + lh);
      const bf16x8 q1f = ldfrag(sm + cur + 32 * 64, l31, ic * 2 + lh);
      a00 = MFMA32(q0f, kf[0][ic], a00);
      a01 = MFMA32(q0f, kf[1][ic], a01);
      a10 = MFMA32(q1f, kf[0][ic], a10);
      a11 = MFMA32(q1f, kf[1][ic], a11);
    }
#pragma unroll
    for (int r = 0; r < 16; ++r) {
      Zc[0][0] += EX2(a00[r]);
      Zc[0][1] += EX2(a01[r]);
      Zc[1][0] += EX2(a10[r]);
      Zc[1][1] += EX2(a11[r]);
    }
  }

#pragma unroll
  for (int kb2 = 0; kb2 < 2; ++kb2) {
    float Zt = Zc[0][kb2] + Zc[1][kb2];
    Zt += __shfl_xor(Zt, 32, 64);
    if (lane < 32)
      zp[((size_t)qh * B_ + b) * F_ + k0 + w * 64 + kb2 * 32 + lane] = Zt;
  }
}

// ---------------------------------------------------------------------------
// Kernel 3: lz[b][k] = -log2(sum of NQS zp planes). 65536 elems (tiny).
// ---------------------------------------------------------------------------
__global__ __launch_bounds__(256) void lzred_k(const float* __restrict__ zp,
                                               float* __restrict__ lz) {
  const int i = blockIdx.x * 256 + threadIdx.x;   // 0 .. B*F-1
  float z = zp[i];
#pragma unroll
  for (int pl = 1; pl < NQS; ++pl) z += zp[(size_t)pl * B_ * F_ + i];
  lz[i] = -LG2(z);
}

// ---------------------------------------------------------------------------
// Kernel 4: partial out over a k-half: out[q,i] = sum_k exp2(S+lz_k)*v[k,i].
// 256 thr / 4 waves, q-tile 128 (32 q per wave -> o=32acc, s=32acc: fits
// ~3 waves/SIMD without spills -- the R10 lesson). KSP=2, 64-k chunks,
// K/VT double-buffered in 32 KB LDS, 1 barrier/chunk.
// lz_k folded in by SEEDING the S-MFMA C-operand with lz (broadcast float4
// loads; replaces zero-init) -> exp2(S) is pre-normalized; no vscale pass.
// 1-D grid, XCD swizzle: bid%32 = g=(b,ks) -> g%8 pins each K/V stream to
// one XCD (4 groups x 1 MB < 4 MB L2 -- R8/R9 lesson).
// ks=0 -> fp32 out; ks=1 -> bf16 partial (reduce_k folds).
// LDS (u16 idx): K dbuf @ 0/4096, VT dbuf @ 8192/12288; Q staged @0 prologue.
// ---------------------------------------------------------------------------
__global__ __launch_bounds__(256, 3) void attn_out_k(
    const u16* __restrict__ qn, const u16* __restrict__ kn,
    const u16* __restrict__ vt, const float* __restrict__ lz,
    float* __restrict__ out, u16* __restrict__ pout) {
  __shared__ __align__(16) u16 sm[16384];   // 32 KB

  const int t = threadIdx.x, lane = t & 63, w = t >> 6;
  const int l31 = lane & 31, lh = lane >> 5;

  const int bid = blockIdx.x;
  const int g = bid & (B_ * KSP - 1);       // same g -> same XCD (mod 8)
  const int qt = bid >> 5;                  // 32 q-tiles of 128
  const int b = g >> 1, ks = g & 1;
  const int q0 = qt * 128;

  // stage Q 128x64 (1024 chunks, 4/thread), hoist own 32-q B-fragments
  const u16* qb = qn + ((size_t)b * F_ + q0) * I_;
#pragma unroll
  for (int p = 0; p < 4; ++p) stage16(sm, qb, p * 256 + t, 64);
  __syncthreads();
  bf16x8 qf[4];
#pragma unroll
  for (int ic = 0; ic < 4; ++ic)
    qf[ic] = ldfrag(sm + (w * 32) * 64, l31, ic * 2 + lh);
  __syncthreads();                          // frag reads done before overwrite

  // hoisted staging offsets: 2 K + 2 V chunks16 per thread per 64-k chunk
  int off_l[2], kg[2], vg[2];
#pragma unroll
  for (int p = 0; p < 2; ++p) {
    const int c = p * 256 + t;
    off_l[p] = soff_l(c);
    kg[p] = soff_g(c, 64);
    vg[p] = soff_g(c, F_);
  }

  const int kofs = ks * (F_ / KSP);
  const u16* ksrc = kn + ((size_t)b * F_ + kofs) * I_;
  const u16* vsrc = vt + (size_t)b * I_ * F_ + kofs;
  const float* lzp = lz + (size_t)b * F_ + kofs + 4 * lh;

  // stage chunk 0 into buffers 0
#pragma unroll
  for (int p = 0; p < 2; ++p) {
    *(int4*)(sm + off_l[p])        = *(const int4*)(ksrc + kg[p]);
    *(int4*)(sm + 8192 + off_l[p]) = *(const int4*)(vsrc + vg[p]);
  }
  ksrc += 64 * I_;
  vsrc += 64;

  f32x16 o0 = ZERO16, o1 = ZERO16;          // [ih]
  const int NC = F_ / KSP / 64;             // 32 chunks

  for (int c = 0; c < NC; ++c) {
    const int cur = (c & 1) * 4096;
    __syncthreads();                        // buf[cur] staged; old readers done
    if (c + 1 < NC) {
      const int nxt = cur ^ 4096;
#pragma unroll
      for (int p = 0; p < 2; ++p) {
        *(int4*)(sm + nxt + off_l[p])        = *(const int4*)(ksrc + kg[p]);
        *(int4*)(sm + 8192 + nxt + off_l[p]) = *(const int4*)(vsrc + vg[p]);
      }
      ksrc += 64 * I_;
      vsrc += 64;
    }

    // seed S with lz (C-reg r: k = z*32 + (r&3)+8*(r>>2)+4*lh; broadcast
    // float4 at k = z*32 + 4*lh + 8*j covers regs 4j..4j+3)
    f32x16 s0, s1;
#pragma unroll
    for (int j = 0; j < 4; ++j) {
      const float4 l0 = *(const float4*)(lzp + c * 64 + 8 * j);
      const float4 l1 = *(const float4*)(lzp + c * 64 + 32 + 8 * j);
      s0[4 * j + 0] = l0.x; s0[4 * j + 1] = l0.y;
      s0[4 * j + 2] = l0.z; s0[4 * j + 3] = l0.w;
      s1[4 * j + 0] = l1.x; s1[4 * j + 1] = l1.y;
      s1[4 * j + 2] = l1.z; s1[4 * j + 3] = l1.w;
    }

    // S^T = K x Q(own 32q): rows=k (2 halves), cols=q
    const u16* Kc = sm + cur;
#pragma unroll
    for (int ic = 0; ic < 4; ++ic) {
      const bf16x8 ak0 = ldfrag(Kc, l31, ic * 2 + lh);
      const bf16x8 ak1 = ldfrag(Kc + 32 * 64, l31, ic * 2 + lh);
      s0 = MFMA32(ak0, qf[ic], s0);
      s1 = MFMA32(ak1, qf[ic], s1);
    }

    // exp2 + in-register transpose into PV A-fragments
    bf16x8 af[4];
    build_af(s0, af[0], af[1]);
    build_af(s1, af[2], af[3]);

    // O += P(32q x 64k) * V(64k x 64i), two i-halves
    const u16* Vc = sm + 8192 + cur;
#pragma unroll
    for (int kq = 0; kq < 4; ++kq) {
      const bf16x8 bv0 = ldfrag(Vc, l31, kq * 2 + lh);
      const bf16x8 bv1 = ldfrag(Vc + 32 * 64, l31, kq * 2 + lh);
      o0 = MFMA32(af[kq], bv0, o0);
      o1 = MFMA32(af[kq], bv1, o1);
    }
  }

  if (ks == 0) {
    float* ob = out + ((size_t)b * F_ + q0 + w * 32) * I_;
#pragma unroll
    for (int r = 0; r < 16; ++r) {
      const int qr = (r & 3) + 8 * (r >> 2) + 4 * lh;   // C/D row mapping
      ob[(size_t)qr * I_ + l31]      = o0[r];
      ob[(size_t)qr * I_ + 32 + l31] = o1[r];
    }
  } else {
    u16* pb = pout + ((size_t)b * F_ + q0 + w * 32) * I_;
#pragma unroll
    for (int r = 0; r < 16; ++r) {
      const int qr = (r & 3) + 8 * (r >> 2) + 4 * lh;
      pb[(size_t)qr * I_ + l31]      = f2b(o0[r]);
      pb[(size_t)qr * I_ + 32 + l31] = f2b(o1[r]);
    }
  }
}

// ---------------------------------------------------------------------------
// Kernel 5: out += bf16 partial (k-split reduction). 8 elems/thread.
// ---------------------------------------------------------------------------
__global__ __launch_bounds__(256) void reduce_k(float* __restrict__ out,
                                                const u16* __restrict__ pout) {
  const size_t i = ((size_t)blockIdx.x * 256 + threadIdx.x) * 8;
  float4 a0 = *(const float4*)(out + i);
  float4 a1 = *(const float4*)(out + i + 4);
  int4 praw = *(const int4*)(pout + i);
  u16 es[8];
  *(int4*)es = praw;
  a0.x += b2f(es[0]); a0.y += b2f(es[1]); a0.z += b2f(es[2]); a0.w += b2f(es[3]);
  a1.x += b2f(es[4]); a1.y += b2f(es[5]); a1.z += b2f(es[6]); a1.w += b2f(es[7]);
  *(float4*)(out + i)     = a0;
  *(float4*)(out + i + 4) = a1;
}

// ---------------------------------------------------------------------------
extern "C" void kernel_launch(void* const* d_in, const int* in_sizes, int n_in,
                              void* d_out, int out_size, void* d_ws,
                              size_t ws_size, hipStream_t stream) {
  const float* x  = (const float*)d_in[0];
  const float* Wq = (const float*)d_in[1];
  const float* Wk = (const float*)d_in[2];
  const float* Wv = (const float*)d_in[3];
  float* out = (float*)d_out;

  // workspace: qn, kn, vt (bf16, B*F*I each); zp (f32 [NQS][B][F]);
  //            lz (f32 [B][F]); pout (bf16 [B][F][I])
  const size_t NBF = (size_t)B_ * F_ * I_;
  u16* qn   = (u16*)d_ws;
  u16* kn   = qn + NBF;
  u16* vt   = kn + NBF;
  float* zp = (float*)(vt + NBF);
  float* lz = zp + (size_t)NQS * B_ * F_;
  u16* pout = (u16*)(lz + (size_t)B_ * F_);

  qkv_ln_k<<<dim3(F_ / 64, B_), 256, 0, stream>>>(x, Wq, Wk, Wv, qn, kn, vt);
  attn_stats_k<<<dim3(F_ / 256, B_, NQS), 256, 0, stream>>>(qn, kn, zp);
  lzred_k<<<dim3(B_ * F_ / 256), 256, 0, stream>>>(zp, lz);
  attn_out_k<<<dim3((F_ / 128) * B_ * KSP), 256, 0, stream>>>(qn, kn, vt, lz, out, pout);
  reduce_k<<<dim3((int)(NBF / 2048)), 256, 0, stream>>>(out, pout);
}